// Round 1
// baseline (306.379 us; speedup 1.0000x reference)
//
#include <hip/hip_runtime.h>

// MultiHeadAttentionRoPE: B=2,S=2048,D=1024,H=16,Dh=64 causal, fp32 in/out,
// bf16 MFMA compute internally (threshold 7.16e-2 = 2% of |out|max allows it).

typedef unsigned short u16;
typedef __bf16 bf16x8 __attribute__((ext_vector_type(8)));
typedef unsigned short u16x8 __attribute__((ext_vector_type(8)));
typedef unsigned short u16x4 __attribute__((ext_vector_type(4)));
typedef float f32x4 __attribute__((ext_vector_type(4)));

#define B_ 2
#define S_ 2048
#define D_ 1024
#define H_ 16
#define DH_ 64
#define BS_ (B_ * S_)
#define N3_ (3 * D_)

__device__ __forceinline__ u16 f2bf(float f) {
  unsigned u = __float_as_uint(f);
  u += 0x7FFFu + ((u >> 16) & 1u);   // RNE
  return (u16)(u >> 16);
}
__device__ __forceinline__ float bf2f(u16 s) {
  return __uint_as_float(((unsigned)s) << 16);
}

union BU { u16x8 u; bf16x8 b; };

__device__ __forceinline__ void store_c(u16* C, size_t i, float v) { C[i] = f2bf(v); }
__device__ __forceinline__ void store_c(float* C, size_t i, float v) { C[i] = v; }

// XOR-swizzle byte-offset bits 4-5 with row bits 2-1: 2-way LDS bank aliasing (free)
#define SWZ(r) ((((r) >> 1) & 3) << 4)

// ---------------- fp32 -> bf16 straight convert (vectorized) ----------------
__global__ __launch_bounds__(256) void k_cvt(const float* __restrict__ in,
                                             u16* __restrict__ out, int n4) {
  int i = blockIdx.x * 256 + threadIdx.x;
  if (i >= n4) return;
  const float4 f = ((const float4*)in)[i];
  u16x4 o;
  o[0] = f2bf(f.x); o[1] = f2bf(f.y); o[2] = f2bf(f.z); o[3] = f2bf(f.w);
  *(u16x4*)(out + (size_t)i * 4) = o;
}

// ---------------- fp32 (R x C) -> bf16 transposed (C x R) ----------------
__global__ __launch_bounds__(256) void k_cvt_T(const float* __restrict__ w,
                                               u16* __restrict__ wT, int R, int C) {
  __shared__ float tl[32][33];
  const int t = threadIdx.x;
  const int lrow = t >> 3, seg = t & 7;
  const int r0 = blockIdx.y * 32, c0 = blockIdx.x * 32;
  const float4 f = *(const float4*)(w + (size_t)(r0 + lrow) * C + c0 + seg * 4);
  tl[lrow][seg * 4 + 0] = f.x; tl[lrow][seg * 4 + 1] = f.y;
  tl[lrow][seg * 4 + 2] = f.z; tl[lrow][seg * 4 + 3] = f.w;
  __syncthreads();
  u16x4 o;
#pragma unroll
  for (int j = 0; j < 4; ++j) o[j] = f2bf(tl[seg * 4 + j][lrow]);
  *(u16x4*)(wT + (size_t)(c0 + lrow) * R + r0 + seg * 4) = o;
}

// ---------------- RoPE cos/sin table (S x 32, fp32, matches JAX fp32 math) ----------------
__global__ __launch_bounds__(256) void k_tab(float* __restrict__ ct, float* __restrict__ st) {
  const int idx = blockIdx.x * 256 + threadIdx.x;  // S_*32 total
  const int tpos = idx >> 5, i = idx & 31;
  const float invf = powf(10000.0f, -(float)i * (1.0f / 32.0f));
  const float a = (float)tpos * invf;
  ct[idx] = cosf(a);
  st[idx] = sinf(a);
}

// ---------------- bf16 GEMM: C[MxN] = A[MxK] * BT[NxK]^T ----------------
// 128x128 tile, 4 waves (2x2), each wave 64x64 = 4x4 mfma_f32_16x16x32_bf16 frags.
template <typename OutT>
__global__ __launch_bounds__(256) void k_gemm(const u16* __restrict__ A,
                                              const u16* __restrict__ BT,
                                              OutT* __restrict__ C,
                                              int M, int N, int K) {
  __shared__ u16 la[128 * 32];
  __shared__ u16 lb[128 * 32];
  const int t = threadIdx.x;
  const int m0 = blockIdx.y * 128, n0 = blockIdx.x * 128;
  const int w = t >> 6, lane = t & 63;
  const int lr = lane & 15, lg = lane >> 4;
  const int wm = (w >> 1) * 64, wn = (w & 1) * 64;
  const int NK = K >> 5;

  // staging: 2 chunks of 16B per thread per tile (rows 0..63 and 64..127)
  const int r0s = t >> 2, i0 = t & 3;
  const int r1s = r0s + 64;

  f32x4 acc[4][4] = {};

  const u16* Ab = A + (size_t)m0 * K;
  const u16* Bb = BT + (size_t)n0 * K;

  u16x8 sa0 = *(const u16x8*)(Ab + (size_t)r0s * K + i0 * 8);
  u16x8 sa1 = *(const u16x8*)(Ab + (size_t)r1s * K + i0 * 8);
  u16x8 sb0 = *(const u16x8*)(Bb + (size_t)r0s * K + i0 * 8);
  u16x8 sb1 = *(const u16x8*)(Bb + (size_t)r1s * K + i0 * 8);
  u16x8 na0 = sa0, na1 = sa1, nb0 = sb0, nb1 = sb1;

  char* laq = (char*)la;
  char* lbq = (char*)lb;
  const int wo0 = r0s * 64 + ((i0 * 16) ^ SWZ(r0s));
  const int wo1 = r1s * 64 + ((i0 * 16) ^ SWZ(r1s));

  for (int kt = 0; kt < NK; ++kt) {
    __syncthreads();
    *(u16x8*)(laq + wo0) = sa0;
    *(u16x8*)(laq + wo1) = sa1;
    *(u16x8*)(lbq + wo0) = sb0;
    *(u16x8*)(lbq + wo1) = sb1;
    __syncthreads();
    if (kt + 1 < NK) {
      const u16* Ak = Ab + (size_t)(kt + 1) * 32;
      const u16* Bk = Bb + (size_t)(kt + 1) * 32;
      na0 = *(const u16x8*)(Ak + (size_t)r0s * K + i0 * 8);
      na1 = *(const u16x8*)(Ak + (size_t)r1s * K + i0 * 8);
      nb0 = *(const u16x8*)(Bk + (size_t)r0s * K + i0 * 8);
      nb1 = *(const u16x8*)(Bk + (size_t)r1s * K + i0 * 8);
    }
    BU af[4], bf_[4];
#pragma unroll
    for (int mi = 0; mi < 4; ++mi) {
      const int row = wm + mi * 16 + lr;
      af[mi].u = *(const u16x8*)(laq + row * 64 + ((lg * 16) ^ SWZ(row)));
      const int rowb = wn + mi * 16 + lr;
      bf_[mi].u = *(const u16x8*)(lbq + rowb * 64 + ((lg * 16) ^ SWZ(rowb)));
    }
#pragma unroll
    for (int mi = 0; mi < 4; ++mi)
#pragma unroll
      for (int ni = 0; ni < 4; ++ni)
        acc[mi][ni] = __builtin_amdgcn_mfma_f32_16x16x32_bf16(af[mi].b, bf_[ni].b,
                                                              acc[mi][ni], 0, 0, 0);
    sa0 = na0; sa1 = na1; sb0 = nb0; sb1 = nb1;
  }

  // C/D layout: col = lane&15, row = (lane>>4)*4 + reg  (m89-verified)
#pragma unroll
  for (int mi = 0; mi < 4; ++mi)
#pragma unroll
    for (int ni = 0; ni < 4; ++ni)
#pragma unroll
      for (int r = 0; r < 4; ++r) {
        const int row = m0 + wm + mi * 16 + lg * 4 + r;
        const int col = n0 + wn + ni * 16 + lr;
        store_c(C, (size_t)row * N + col, acc[mi][ni][r]);
      }
}

// ---------------- RoPE + head layout + V transpose ----------------
// qkv (BS x 3072) bf16 -> Q,K [bh][s][dh] (rope'd), Vt [bh][dh][s]
__global__ __launch_bounds__(256) void k_prep(const u16* __restrict__ qkv,
                                              const float* __restrict__ ct,
                                              const float* __restrict__ st,
                                              u16* __restrict__ Q, u16* __restrict__ K,
                                              u16* __restrict__ Vt) {
  __shared__ u16 vl[64][72];
  const int stile = blockIdx.x, bh = blockIdx.y;
  const int b = bh >> 4, h = bh & 15;
  const int t = threadIdx.x;
  const int row = t >> 2, qr = t & 3;
  const int s = stile * 64 + row;
  const u16* base = qkv + (size_t)(b * S_ + s) * N3_ + h * DH_;
  const int d0 = qr * 8;  // pair-halves d0..d0+7 and +32
  float c[8], sn[8];
#pragma unroll
  for (int j = 0; j < 8; ++j) {
    c[j] = ct[s * 32 + d0 + j];
    sn[j] = st[s * 32 + d0 + j];
  }
#pragma unroll
  for (int part = 0; part < 2; ++part) {
    const u16* src = base + part * D_;
    u16x8 lo = *(const u16x8*)(src + d0);
    u16x8 hi = *(const u16x8*)(src + d0 + 32);
    u16x8 olo, ohi;
#pragma unroll
    for (int j = 0; j < 8; ++j) {
      float x1 = bf2f(lo[j]), x2 = bf2f(hi[j]);
      olo[j] = f2bf(x1 * c[j] - x2 * sn[j]);
      ohi[j] = f2bf(x2 * c[j] + x1 * sn[j]);
    }
    u16* dst = (part ? K : Q) + ((size_t)bh * S_ + s) * DH_;
    *(u16x8*)(dst + d0) = olo;
    *(u16x8*)(dst + d0 + 32) = ohi;
  }
  // V transpose through LDS (64 s-rows x 64 dh -> 64 dh-rows x 64 s)
  u16x8 v0 = *(const u16x8*)(base + 2 * D_ + qr * 16);
  u16x8 v1 = *(const u16x8*)(base + 2 * D_ + qr * 16 + 8);
#pragma unroll
  for (int j = 0; j < 8; ++j) {
    vl[qr * 16 + j][row] = v0[j];
    vl[qr * 16 + 8 + j][row] = v1[j];
  }
  __syncthreads();
  const int dh = row, sc = qr * 16;
  u16x8 o0, o1;
#pragma unroll
  for (int j = 0; j < 8; ++j) { o0[j] = vl[dh][sc + j]; o1[j] = vl[dh][sc + 8 + j]; }
  u16* vdst = Vt + ((size_t)bh * DH_ + dh) * S_ + stile * 64 + sc;
  *(u16x8*)vdst = o0;
  *(u16x8*)(vdst + 8) = o1;
}

// ---------------- causal flash attention ----------------
// grid (S/64, B*H); 4 independent waves x 16 q-rows; kv-tiles of 32.
__global__ __launch_bounds__(256) void k_attn(const u16* __restrict__ Q,
                                              const u16* __restrict__ K,
                                              const u16* __restrict__ Vt,
                                              u16* __restrict__ Ao) {
  __shared__ u16 pl[4][16 * 32];  // per-wave P transpose buffer (swizzled 64B rows)
  const int qt = blockIdx.x, bh = blockIdx.y;
  const int w = threadIdx.x >> 6, lane = threadIdx.x & 63;
  const int lr = lane & 15, lg = lane >> 4;
  const int q0 = qt * 64 + w * 16;
  char* myp = (char*)pl[w];

  const u16* Qb = Q + ((size_t)bh * S_ + q0) * DH_;
  BU qa0, qa1;
  qa0.u = *(const u16x8*)(Qb + lr * DH_ + lg * 8);
  qa1.u = *(const u16x8*)(Qb + lr * DH_ + 32 + lg * 8);

  f32x4 o[4] = {};
  float m[4], l[4] = {};
#pragma unroll
  for (int r = 0; r < 4; ++r) m[r] = -1e30f;

  const int ntile = ((q0 + 15) >> 5) + 1;  // causal: only kv0 <= q0+15
  const u16* Kbh = K + (size_t)bh * S_ * DH_;
  const u16* Vbh = Vt + (size_t)bh * DH_ * S_;

  for (int it = 0; it < ntile; ++it) {
    const int kv0 = it * 32;
    f32x4 s0 = {}, s1 = {};
    {
      BU b0, b1;
      b0.u = *(const u16x8*)(Kbh + (size_t)(kv0 + lr) * DH_ + lg * 8);
      b1.u = *(const u16x8*)(Kbh + (size_t)(kv0 + lr) * DH_ + 32 + lg * 8);
      s0 = __builtin_amdgcn_mfma_f32_16x16x32_bf16(qa0.b, b0.b, s0, 0, 0, 0);
      s0 = __builtin_amdgcn_mfma_f32_16x16x32_bf16(qa1.b, b1.b, s0, 0, 0, 0);
      b0.u = *(const u16x8*)(Kbh + (size_t)(kv0 + 16 + lr) * DH_ + lg * 8);
      b1.u = *(const u16x8*)(Kbh + (size_t)(kv0 + 16 + lr) * DH_ + 32 + lg * 8);
      s1 = __builtin_amdgcn_mfma_f32_16x16x32_bf16(qa0.b, b0.b, s1, 0, 0, 0);
      s1 = __builtin_amdgcn_mfma_f32_16x16x32_bf16(qa1.b, b1.b, s1, 0, 0, 0);
    }
    float p0[4], p1[4];
#pragma unroll
    for (int r = 0; r < 4; ++r) { p0[r] = s0[r] * 0.125f; p1[r] = s1[r] * 0.125f; }
    if (kv0 + 31 > q0) {  // wave-uniform: tiles overlapping the diagonal
#pragma unroll
      for (int r = 0; r < 4; ++r) {
        const int rowq = q0 + lg * 4 + r;
        if (kv0 + lr > rowq) p0[r] = -1e30f;
        if (kv0 + 16 + lr > rowq) p1[r] = -1e30f;
      }
    }
    float mx[4];
#pragma unroll
    for (int r = 0; r < 4; ++r) mx[r] = fmaxf(p0[r], p1[r]);
#pragma unroll
    for (int off = 1; off < 16; off <<= 1)
#pragma unroll
      for (int r = 0; r < 4; ++r) mx[r] = fmaxf(mx[r], __shfl_xor(mx[r], off, 64));
    float al[4], sm[4];
#pragma unroll
    for (int r = 0; r < 4; ++r) {
      const float mn = fmaxf(m[r], mx[r]);
      al[r] = __expf(m[r] - mn);
      m[r] = mn;
      p0[r] = __expf(p0[r] - mn);
      p1[r] = __expf(p1[r] - mn);
      sm[r] = p0[r] + p1[r];
    }
#pragma unroll
    for (int off = 1; off < 16; off <<= 1)
#pragma unroll
      for (int r = 0; r < 4; ++r) sm[r] += __shfl_xor(sm[r], off, 64);
#pragma unroll
    for (int r = 0; r < 4; ++r) l[r] = l[r] * al[r] + sm[r];
#pragma unroll
    for (int d = 0; d < 4; ++d)
#pragma unroll
      for (int r = 0; r < 4; ++r) o[d][r] *= al[r];
    // P (C-layout) -> per-wave LDS -> A-layout fragment
#pragma unroll
    for (int r = 0; r < 4; ++r) {
      const int prow = lg * 4 + r;
      *(u16*)(myp + prow * 64 + ((lr * 2) ^ SWZ(prow))) = f2bf(p0[r]);
      *(u16*)(myp + prow * 64 + (((16 + lr) * 2) ^ SWZ(prow))) = f2bf(p1[r]);
    }
    BU pa;
    pa.u = *(const u16x8*)(myp + lr * 64 + ((lg * 16) ^ SWZ(lr)));
#pragma unroll
    for (int d = 0; d < 4; ++d) {
      BU vb;
      vb.u = *(const u16x8*)(Vbh + (size_t)(d * 16 + lr) * S_ + kv0 + lg * 8);
      o[d] = __builtin_amdgcn_mfma_f32_16x16x32_bf16(pa.b, vb.b, o[d], 0, 0, 0);
    }
  }
  const int b = bh >> 4, h = bh & 15;
#pragma unroll
  for (int r = 0; r < 4; ++r) {
    const float inv = 1.0f / l[r];
    const size_t rowo = ((size_t)b * S_ + q0 + lg * 4 + r) * D_ + h * DH_;
#pragma unroll
    for (int d = 0; d < 4; ++d)
      Ao[rowo + d * 16 + lr] = f2bf(o[d][r] * inv);
  }
}

// ---------------- launch ----------------
extern "C" void kernel_launch(void* const* d_in, const int* in_sizes, int n_in,
                              void* d_out, int out_size, void* d_ws, size_t ws_size,
                              hipStream_t stream) {
  const float* x = (const float*)d_in[0];
  const float* wqkv = (const float*)d_in[1];
  const float* wproj = (const float*)d_in[2];
  float* out = (float*)d_out;
  char* ws = (char*)d_ws;

  // workspace layout (~72.5 MB total)
  u16* xb      = (u16*)(ws + 0);          //  8 MB  x bf16 (4096x1024)
  u16* wqkvT   = (u16*)(ws + 8388608);    //  6 MB  w_qkv^T bf16 (3072x1024)
  u16* wprojT  = (u16*)(ws + 14680064);   //  2 MB  w_proj^T bf16 (1024x1024)
  u16* qkvb    = (u16*)(ws + 16777216);   // 24 MB  qkv bf16 (4096x3072)
  u16* Qb      = (u16*)(ws + 41943040);   //  8 MB  [bh][s][dh]
  u16* Kb      = (u16*)(ws + 50331648);   //  8 MB  [bh][s][dh]
  u16* Vtb     = (u16*)(ws + 58720256);   //  8 MB  [bh][dh][s]
  u16* aob     = (u16*)(ws + 67108864);   //  8 MB  attn out (4096x1024)
  float* ct    = (float*)(ws + 75497472); // 256 KB cos table (S x 32)
  float* stab  = (float*)(ws + 75759616); // 256 KB sin table

  k_cvt<<<4096, 256, 0, stream>>>(x, xb, BS_ * D_ / 4);
  k_cvt_T<<<dim3(96, 32), 256, 0, stream>>>(wqkv, wqkvT, D_, N3_);
  k_cvt_T<<<dim3(32, 32), 256, 0, stream>>>(wproj, wprojT, D_, D_);
  k_tab<<<256, 256, 0, stream>>>(ct, stab);

  k_gemm<u16><<<dim3(24, 32), 256, 0, stream>>>(xb, wqkvT, qkvb, BS_, N3_, D_);
  k_prep<<<dim3(32, 32), 256, 0, stream>>>(qkvb, ct, stab, Qb, Kb, Vtb);
  k_attn<<<dim3(32, 32), 256, 0, stream>>>(Qb, Kb, Vtb, aob);
  k_gemm<float><<<dim3(8, 32), 256, 0, stream>>>(aob, wprojT, out, BS_, D_, D_);
}

// Round 2
// 203.402 us; speedup vs baseline: 1.5063x; 1.5063x over previous
//
#include <hip/hip_runtime.h>

// MultiHeadAttentionRoPE: B=2,S=2048,D=1024,H=16,Dh=64 causal, fp32 in/out,
// bf16 MFMA compute internally (threshold 7.16e-2 = 2% of |out|max allows it).

typedef unsigned short u16;
typedef __bf16 bf16x8 __attribute__((ext_vector_type(8)));
typedef unsigned short u16x8 __attribute__((ext_vector_type(8)));
typedef unsigned short u16x4 __attribute__((ext_vector_type(4)));
typedef float f32x4 __attribute__((ext_vector_type(4)));

#define B_ 2
#define S_ 2048
#define D_ 1024
#define H_ 16
#define DH_ 64
#define BS_ (B_ * S_)
#define N3_ (3 * D_)

__device__ __forceinline__ u16 f2bf(float f) {
  unsigned u = __float_as_uint(f);
  u += 0x7FFFu + ((u >> 16) & 1u);   // RNE
  return (u16)(u >> 16);
}
__device__ __forceinline__ float bf2f(u16 s) {
  return __uint_as_float(((unsigned)s) << 16);
}

union BU { u16x8 u; bf16x8 b; };

__device__ __forceinline__ void store_c(u16* C, size_t i, float v) { C[i] = f2bf(v); }
__device__ __forceinline__ void store_c(float* C, size_t i, float v) { C[i] = v; }

// XOR-swizzle byte-offset bits 4-5 with row bits 2-1: 2-way LDS bank aliasing (free)
#define SWZ(r) ((((r) >> 1) & 3) << 4)

// ---------------- fp32 -> bf16 straight convert (vectorized) ----------------
__global__ __launch_bounds__(256) void k_cvt(const float* __restrict__ in,
                                             u16* __restrict__ out, int n4) {
  int i = blockIdx.x * 256 + threadIdx.x;
  if (i >= n4) return;
  const float4 f = ((const float4*)in)[i];
  u16x4 o;
  o[0] = f2bf(f.x); o[1] = f2bf(f.y); o[2] = f2bf(f.z); o[3] = f2bf(f.w);
  *(u16x4*)(out + (size_t)i * 4) = o;
}

// ---------------- fp32 (R x C) -> bf16 transposed (C x R) ----------------
__global__ __launch_bounds__(256) void k_cvt_T(const float* __restrict__ w,
                                               u16* __restrict__ wT, int R, int C) {
  __shared__ float tl[32][33];
  const int t = threadIdx.x;
  const int lrow = t >> 3, seg = t & 7;
  const int r0 = blockIdx.y * 32, c0 = blockIdx.x * 32;
  const float4 f = *(const float4*)(w + (size_t)(r0 + lrow) * C + c0 + seg * 4);
  tl[lrow][seg * 4 + 0] = f.x; tl[lrow][seg * 4 + 1] = f.y;
  tl[lrow][seg * 4 + 2] = f.z; tl[lrow][seg * 4 + 3] = f.w;
  __syncthreads();
  u16x4 o;
#pragma unroll
  for (int j = 0; j < 4; ++j) o[j] = f2bf(tl[seg * 4 + j][lrow]);
  *(u16x4*)(wT + (size_t)(c0 + lrow) * R + r0 + seg * 4) = o;
}

// ---------------- RoPE cos/sin table (S x 32, fp32, matches JAX fp32 math) ----------------
__global__ __launch_bounds__(256) void k_tab(float* __restrict__ ct, float* __restrict__ st) {
  const int idx = blockIdx.x * 256 + threadIdx.x;  // S_*32 total
  const int tpos = idx >> 5, i = idx & 31;
  const float invf = powf(10000.0f, -(float)i * (1.0f / 32.0f));
  const float a = (float)tpos * invf;
  ct[idx] = cosf(a);
  st[idx] = sinf(a);
}

// ---------------- bf16 GEMM: C[MxN] = A[MxK] * BT[NxK]^T ----------------
// 128x128 tile, 4 waves (2x2), each wave 64x64 = 4x4 mfma_f32_16x16x32_bf16 frags.
template <typename OutT>
__global__ __launch_bounds__(256) void k_gemm(const u16* __restrict__ A,
                                              const u16* __restrict__ BT,
                                              OutT* __restrict__ C,
                                              int M, int N, int K) {
  __shared__ u16 la[128 * 32];
  __shared__ u16 lb[128 * 32];
  const int t = threadIdx.x;
  const int m0 = blockIdx.y * 128, n0 = blockIdx.x * 128;
  const int w = t >> 6, lane = t & 63;
  const int lr = lane & 15, lg = lane >> 4;
  const int wm = (w >> 1) * 64, wn = (w & 1) * 64;
  const int NK = K >> 5;

  // staging: 2 chunks of 16B per thread per tile (rows 0..63 and 64..127)
  const int r0s = t >> 2, i0 = t & 3;
  const int r1s = r0s + 64;

  f32x4 acc[4][4] = {};

  const u16* Ab = A + (size_t)m0 * K;
  const u16* Bb = BT + (size_t)n0 * K;

  u16x8 sa0 = *(const u16x8*)(Ab + (size_t)r0s * K + i0 * 8);
  u16x8 sa1 = *(const u16x8*)(Ab + (size_t)r1s * K + i0 * 8);
  u16x8 sb0 = *(const u16x8*)(Bb + (size_t)r0s * K + i0 * 8);
  u16x8 sb1 = *(const u16x8*)(Bb + (size_t)r1s * K + i0 * 8);
  u16x8 na0 = sa0, na1 = sa1, nb0 = sb0, nb1 = sb1;

  char* laq = (char*)la;
  char* lbq = (char*)lb;
  const int wo0 = r0s * 64 + ((i0 * 16) ^ SWZ(r0s));
  const int wo1 = r1s * 64 + ((i0 * 16) ^ SWZ(r1s));

  for (int kt = 0; kt < NK; ++kt) {
    __syncthreads();
    *(u16x8*)(laq + wo0) = sa0;
    *(u16x8*)(laq + wo1) = sa1;
    *(u16x8*)(lbq + wo0) = sb0;
    *(u16x8*)(lbq + wo1) = sb1;
    __syncthreads();
    if (kt + 1 < NK) {
      const u16* Ak = Ab + (size_t)(kt + 1) * 32;
      const u16* Bk = Bb + (size_t)(kt + 1) * 32;
      na0 = *(const u16x8*)(Ak + (size_t)r0s * K + i0 * 8);
      na1 = *(const u16x8*)(Ak + (size_t)r1s * K + i0 * 8);
      nb0 = *(const u16x8*)(Bk + (size_t)r0s * K + i0 * 8);
      nb1 = *(const u16x8*)(Bk + (size_t)r1s * K + i0 * 8);
    }
    BU af[4], bf_[4];
#pragma unroll
    for (int mi = 0; mi < 4; ++mi) {
      const int row = wm + mi * 16 + lr;
      af[mi].u = *(const u16x8*)(laq + row * 64 + ((lg * 16) ^ SWZ(row)));
      const int rowb = wn + mi * 16 + lr;
      bf_[mi].u = *(const u16x8*)(lbq + rowb * 64 + ((lg * 16) ^ SWZ(rowb)));
    }
#pragma unroll
    for (int mi = 0; mi < 4; ++mi)
#pragma unroll
      for (int ni = 0; ni < 4; ++ni)
        acc[mi][ni] = __builtin_amdgcn_mfma_f32_16x16x32_bf16(af[mi].b, bf_[ni].b,
                                                              acc[mi][ni], 0, 0, 0);
    sa0 = na0; sa1 = na1; sb0 = nb0; sb1 = nb1;
  }

  // C/D layout: col = lane&15, row = (lane>>4)*4 + reg  (m89-verified)
#pragma unroll
  for (int mi = 0; mi < 4; ++mi)
#pragma unroll
    for (int ni = 0; ni < 4; ++ni)
#pragma unroll
      for (int r = 0; r < 4; ++r) {
        const int row = m0 + wm + mi * 16 + lg * 4 + r;
        const int col = n0 + wn + ni * 16 + lr;
        store_c(C, (size_t)row * N + col, acc[mi][ni][r]);
      }
}

// ---------------- RoPE + head layout + V transpose ----------------
// qkv (BS x 3072) bf16 -> Q,K [bh][s][dh] (rope'd), Vt [bh][dh][s]
__global__ __launch_bounds__(256) void k_prep(const u16* __restrict__ qkv,
                                              const float* __restrict__ ct,
                                              const float* __restrict__ st,
                                              u16* __restrict__ Q, u16* __restrict__ K,
                                              u16* __restrict__ Vt) {
  __shared__ u16 vl[64][72];
  const int stile = blockIdx.x, bh = blockIdx.y;
  const int b = bh >> 4, h = bh & 15;
  const int t = threadIdx.x;
  const int row = t >> 2, qr = t & 3;
  const int s = stile * 64 + row;
  const u16* base = qkv + (size_t)(b * S_ + s) * N3_ + h * DH_;
  const int d0 = qr * 8;  // pair-halves d0..d0+7 and +32
  float c[8], sn[8];
#pragma unroll
  for (int j = 0; j < 8; ++j) {
    c[j] = ct[s * 32 + d0 + j];
    sn[j] = st[s * 32 + d0 + j];
  }
#pragma unroll
  for (int part = 0; part < 2; ++part) {
    const u16* src = base + part * D_;
    u16x8 lo = *(const u16x8*)(src + d0);
    u16x8 hi = *(const u16x8*)(src + d0 + 32);
    u16x8 olo, ohi;
#pragma unroll
    for (int j = 0; j < 8; ++j) {
      float x1 = bf2f(lo[j]), x2 = bf2f(hi[j]);
      olo[j] = f2bf(x1 * c[j] - x2 * sn[j]);
      ohi[j] = f2bf(x2 * c[j] + x1 * sn[j]);
    }
    u16* dst = (part ? K : Q) + ((size_t)bh * S_ + s) * DH_;
    *(u16x8*)(dst + d0) = olo;
    *(u16x8*)(dst + d0 + 32) = ohi;
  }
  // V transpose through LDS (64 s-rows x 64 dh -> 64 dh-rows x 64 s)
  u16x8 v0 = *(const u16x8*)(base + 2 * D_ + qr * 16);
  u16x8 v1 = *(const u16x8*)(base + 2 * D_ + qr * 16 + 8);
#pragma unroll
  for (int j = 0; j < 8; ++j) {
    vl[qr * 16 + j][row] = v0[j];
    vl[qr * 16 + 8 + j][row] = v1[j];
  }
  __syncthreads();
  const int dh = row, sc = qr * 16;
  u16x8 o0, o1;
#pragma unroll
  for (int j = 0; j < 8; ++j) { o0[j] = vl[dh][sc + j]; o1[j] = vl[dh][sc + 8 + j]; }
  u16* vdst = Vt + ((size_t)bh * DH_ + dh) * S_ + stile * 64 + sc;
  *(u16x8*)vdst = o0;
  *(u16x8*)(vdst + 8) = o1;
}

// ---------------- causal flash attention, swapped-operand form ----------------
// One wave per block; wave owns 16 q-columns, iterates kv tiles of 64.
// S^T = K·Q^T  (A=K rows=kv, B=Q cols=q)  -> lane holds 16 kv values of ONE q col
// => softmax row-reduce = 15 in-lane ops + 2 shfl_xor. Per-lane scalar m,l.
// PV swapped:  O^T = V^T · P^T  (A=V^T rows=dh, B=P^T via per-wave LDS transpose).
__global__ __launch_bounds__(64, 4) void k_attn(const u16* __restrict__ Q,
                                                const u16* __restrict__ K,
                                                const u16* __restrict__ Vt,
                                                u16* __restrict__ Ao) {
  __shared__ char pl[16 * 144];   // P^T staging: 16 q-rows x 64 kv bf16, 144B pitch
  const int bid = blockIdx.x;
  const int qi = bid >> 5;        // 0..127
  const int bh = bid & 31;
  const int qt = 127 - qi;        // longest q-tiles scheduled first
  const int q0 = qt * 16;
  const int lane = threadIdx.x;
  const int lr = lane & 15, lg = lane >> 4;

  const u16* Qb = Q + ((size_t)bh * S_ + q0) * DH_;
  BU qf0, qf1;                    // B-operand: lane holds Q[q0+lr][k=lg*8+j]
  qf0.u = *(const u16x8*)(Qb + lr * DH_ + lg * 8);
  qf1.u = *(const u16x8*)(Qb + lr * DH_ + 32 + lg * 8);

  f32x4 o[4] = {};                // O^T acc: o[d] row=d*16+lg*4+r (dh), col=lr (q)
  float m = -1e30f, l = 0.f;

  const u16* Kbh = K + (size_t)bh * S_ * DH_;
  const u16* Vbh = Vt + (size_t)bh * DH_ * S_;
  const int ntile = (q0 >> 6) + 1;

  for (int it = 0; it < ntile; ++it) {
    const int kv0 = it * 64;
    f32x4 s[4] = {};
#pragma unroll
    for (int kvb = 0; kvb < 4; ++kvb) {
      const u16* Kr = Kbh + (size_t)(kv0 + kvb * 16 + lr) * DH_;
      BU k0, k1;
      k0.u = *(const u16x8*)(Kr + lg * 8);
      k1.u = *(const u16x8*)(Kr + 32 + lg * 8);
      s[kvb] = __builtin_amdgcn_mfma_f32_16x16x32_bf16(k0.b, qf0.b, s[kvb], 0, 0, 0);
      s[kvb] = __builtin_amdgcn_mfma_f32_16x16x32_bf16(k1.b, qf1.b, s[kvb], 0, 0, 0);
    }
    // p[kvb*4+r] = S^T[kv0+kvb*16+lg*4+r][q0+lr] * scale
    float p[16];
#pragma unroll
    for (int kvb = 0; kvb < 4; ++kvb)
#pragma unroll
      for (int r = 0; r < 4; ++r) p[kvb * 4 + r] = s[kvb][r] * 0.125f;
    if (kv0 + 63 > q0) {          // only the diagonal-crossing tile masks
#pragma unroll
      for (int kvb = 0; kvb < 4; ++kvb)
#pragma unroll
        for (int r = 0; r < 4; ++r)
          if (kv0 + kvb * 16 + lg * 4 + r > q0 + lr) p[kvb * 4 + r] = -1e30f;
    }
    float mx = p[0];
#pragma unroll
    for (int i = 1; i < 16; ++i) mx = fmaxf(mx, p[i]);
    mx = fmaxf(mx, __shfl_xor(mx, 16, 64));
    mx = fmaxf(mx, __shfl_xor(mx, 32, 64));
    const float mn = fmaxf(m, mx);
    const float al = __expf(m - mn);
    m = mn;
    float sm = 0.f;
#pragma unroll
    for (int i = 0; i < 16; ++i) { p[i] = __expf(p[i] - mn); sm += p[i]; }
    sm += __shfl_xor(sm, 16, 64);
    sm += __shfl_xor(sm, 32, 64);
    l = l * al + sm;
#pragma unroll
    for (int d = 0; d < 4; ++d)
#pragma unroll
      for (int r = 0; r < 4; ++r) o[d][r] *= al;
    // P^T -> LDS as P[q=lr][kv]: 4x ds_write_b64, then 2x b128 B-frag reads.
#pragma unroll
    for (int kvb = 0; kvb < 4; ++kvb) {
      u16x4 w;
#pragma unroll
      for (int r = 0; r < 4; ++r) w[r] = f2bf(p[kvb * 4 + r]);
      *(u16x4*)(pl + lr * 144 + kvb * 32 + lg * 8) = w;
    }
    BU pf0, pf1;                  // B-operand: P^T[k=lg*8+j][col=lr]
    pf0.u = *(const u16x8*)(pl + lr * 144 + lg * 16);
    pf1.u = *(const u16x8*)(pl + lr * 144 + 64 + lg * 16);
#pragma unroll
    for (int d = 0; d < 4; ++d) {
      const u16* Vr = Vbh + (size_t)(d * 16 + lr) * S_ + kv0;
      BU v0, v1;
      v0.u = *(const u16x8*)(Vr + lg * 8);
      v1.u = *(const u16x8*)(Vr + 32 + lg * 8);
      o[d] = __builtin_amdgcn_mfma_f32_16x16x32_bf16(v0.b, pf0.b, o[d], 0, 0, 0);
      o[d] = __builtin_amdgcn_mfma_f32_16x16x32_bf16(v1.b, pf1.b, o[d], 0, 0, 0);
    }
  }

  const float inv = 1.0f / l;
  const int b = bh >> 4, h = bh & 15;
  const size_t rowo = ((size_t)b * S_ + q0 + lr) * D_ + h * DH_;
#pragma unroll
  for (int d = 0; d < 4; ++d) {
    u16x4 w;
#pragma unroll
    for (int r = 0; r < 4; ++r) w[r] = f2bf(o[d][r] * inv);
    *(u16x4*)(Ao + rowo + d * 16 + lg * 4) = w;
  }
}

// ---------------- launch ----------------
extern "C" void kernel_launch(void* const* d_in, const int* in_sizes, int n_in,
                              void* d_out, int out_size, void* d_ws, size_t ws_size,
                              hipStream_t stream) {
  const float* x = (const float*)d_in[0];
  const float* wqkv = (const float*)d_in[1];
  const float* wproj = (const float*)d_in[2];
  float* out = (float*)d_out;
  char* ws = (char*)d_ws;

  // workspace layout (~76 MB total)
  u16* xb      = (u16*)(ws + 0);          //  8 MB  x bf16 (4096x1024)
  u16* wqkvT   = (u16*)(ws + 8388608);    //  6 MB  w_qkv^T bf16 (3072x1024)
  u16* wprojT  = (u16*)(ws + 14680064);   //  2 MB  w_proj^T bf16 (1024x1024)
  u16* qkvb    = (u16*)(ws + 16777216);   // 24 MB  qkv bf16 (4096x3072)
  u16* Qb      = (u16*)(ws + 41943040);   //  8 MB  [bh][s][dh]
  u16* Kb      = (u16*)(ws + 50331648);   //  8 MB  [bh][s][dh]
  u16* Vtb     = (u16*)(ws + 58720256);   //  8 MB  [bh][dh][s]
  u16* aob     = (u16*)(ws + 67108864);   //  8 MB  attn out (4096x1024)
  float* ct    = (float*)(ws + 75497472); // 256 KB cos table (S x 32)
  float* stab  = (float*)(ws + 75759616); // 256 KB sin table

  k_cvt<<<4096, 256, 0, stream>>>(x, xb, BS_ * D_ / 4);
  k_cvt_T<<<dim3(96, 32), 256, 0, stream>>>(wqkv, wqkvT, D_, N3_);
  k_cvt_T<<<dim3(32, 32), 256, 0, stream>>>(wproj, wprojT, D_, D_);
  k_tab<<<256, 256, 0, stream>>>(ct, stab);

  k_gemm<u16><<<dim3(24, 32), 256, 0, stream>>>(xb, wqkvT, qkvb, BS_, N3_, D_);
  k_prep<<<dim3(32, 32), 256, 0, stream>>>(qkvb, ct, stab, Qb, Kb, Vtb);
  k_attn<<<4096, 64, 0, stream>>>(Qb, Kb, Vtb, aob);
  k_gemm<float><<<dim3(8, 32), 256, 0, stream>>>(aob, wprojT, out, BS_, D_, D_);
}

// Round 3
// 126.455 us; speedup vs baseline: 2.4228x; 1.6085x over previous
//
#include <hip/hip_runtime.h>

// MultiHeadAttentionRoPE: B=2,S=2048,D=1024,H=16,Dh=64 causal, fp32 in/out,
// bf16 MFMA compute internally (threshold 7.16e-2 = 2% of |out|max allows it).

typedef unsigned short u16;
typedef __bf16 bf16x8 __attribute__((ext_vector_type(8)));
typedef unsigned short u16x8 __attribute__((ext_vector_type(8)));
typedef unsigned short u16x4 __attribute__((ext_vector_type(4)));
typedef float f32x4 __attribute__((ext_vector_type(4)));

#define B_ 2
#define S_ 2048
#define D_ 1024
#define H_ 16
#define DH_ 64
#define BS_ (B_ * S_)
#define N3_ (3 * D_)

__device__ __forceinline__ u16 f2bf(float f) {
  unsigned u = __float_as_uint(f);
  u += 0x7FFFu + ((u >> 16) & 1u);   // RNE
  return (u16)(u >> 16);
}
__device__ __forceinline__ float bf2f(u16 s) {
  return __uint_as_float(((unsigned)s) << 16);
}

union BU { u16x8 u; bf16x8 b; };

__device__ __forceinline__ void store_c(u16* C, size_t i, float v) { C[i] = f2bf(v); }
__device__ __forceinline__ void store_c(float* C, size_t i, float v) { C[i] = v; }

// XOR-swizzle byte-offset bits 4-5 with row bits 2-1: 2-way LDS bank aliasing (free)
#define SWZ(r) ((((r) >> 1) & 3) << 4)

// ---------------- fp32 -> bf16 straight convert (vectorized) ----------------
__global__ __launch_bounds__(256) void k_cvt(const float* __restrict__ in,
                                             u16* __restrict__ out, int n4) {
  int i = blockIdx.x * 256 + threadIdx.x;
  if (i >= n4) return;
  const float4 f = ((const float4*)in)[i];
  u16x4 o;
  o[0] = f2bf(f.x); o[1] = f2bf(f.y); o[2] = f2bf(f.z); o[3] = f2bf(f.w);
  *(u16x4*)(out + (size_t)i * 4) = o;
}

// ---------------- fp32 (R x C) -> bf16 transposed (C x R) ----------------
__global__ __launch_bounds__(256) void k_cvt_T(const float* __restrict__ w,
                                               u16* __restrict__ wT, int R, int C) {
  __shared__ float tl[32][33];
  const int t = threadIdx.x;
  const int lrow = t >> 3, seg = t & 7;
  const int r0 = blockIdx.y * 32, c0 = blockIdx.x * 32;
  const float4 f = *(const float4*)(w + (size_t)(r0 + lrow) * C + c0 + seg * 4);
  tl[lrow][seg * 4 + 0] = f.x; tl[lrow][seg * 4 + 1] = f.y;
  tl[lrow][seg * 4 + 2] = f.z; tl[lrow][seg * 4 + 3] = f.w;
  __syncthreads();
  u16x4 o;
#pragma unroll
  for (int j = 0; j < 4; ++j) o[j] = f2bf(tl[seg * 4 + j][lrow]);
  *(u16x4*)(wT + (size_t)(c0 + lrow) * R + r0 + seg * 4) = o;
}

// ---------------- RoPE cos/sin table (S x 32, fp32, matches JAX fp32 math) ----------------
__global__ __launch_bounds__(256) void k_tab(float* __restrict__ ct, float* __restrict__ st) {
  const int idx = blockIdx.x * 256 + threadIdx.x;  // S_*32 total
  const int tpos = idx >> 5, i = idx & 31;
  const float invf = powf(10000.0f, -(float)i * (1.0f / 32.0f));
  const float a = (float)tpos * invf;
  ct[idx] = cosf(a);
  st[idx] = sinf(a);
}

// ---------------- bf16 GEMM: C[MxN] = A[MxK] * BT[NxK]^T ----------------
// 128x128 tile, 4 waves (2x2), each wave 64x64 = 4x4 mfma_f32_16x16x32_bf16 frags.
template <typename OutT>
__global__ __launch_bounds__(256) void k_gemm(const u16* __restrict__ A,
                                              const u16* __restrict__ BT,
                                              OutT* __restrict__ C,
                                              int M, int N, int K) {
  __shared__ u16 la[128 * 32];
  __shared__ u16 lb[128 * 32];
  const int t = threadIdx.x;
  const int m0 = blockIdx.y * 128, n0 = blockIdx.x * 128;
  const int w = t >> 6, lane = t & 63;
  const int lr = lane & 15, lg = lane >> 4;
  const int wm = (w >> 1) * 64, wn = (w & 1) * 64;
  const int NK = K >> 5;

  // staging: 2 chunks of 16B per thread per tile (rows 0..63 and 64..127)
  const int r0s = t >> 2, i0 = t & 3;
  const int r1s = r0s + 64;

  f32x4 acc[4][4] = {};

  const u16* Ab = A + (size_t)m0 * K;
  const u16* Bb = BT + (size_t)n0 * K;

  u16x8 sa0 = *(const u16x8*)(Ab + (size_t)r0s * K + i0 * 8);
  u16x8 sa1 = *(const u16x8*)(Ab + (size_t)r1s * K + i0 * 8);
  u16x8 sb0 = *(const u16x8*)(Bb + (size_t)r0s * K + i0 * 8);
  u16x8 sb1 = *(const u16x8*)(Bb + (size_t)r1s * K + i0 * 8);
  u16x8 na0 = sa0, na1 = sa1, nb0 = sb0, nb1 = sb1;

  char* laq = (char*)la;
  char* lbq = (char*)lb;
  const int wo0 = r0s * 64 + ((i0 * 16) ^ SWZ(r0s));
  const int wo1 = r1s * 64 + ((i0 * 16) ^ SWZ(r1s));

  for (int kt = 0; kt < NK; ++kt) {
    __syncthreads();
    *(u16x8*)(laq + wo0) = sa0;
    *(u16x8*)(laq + wo1) = sa1;
    *(u16x8*)(lbq + wo0) = sb0;
    *(u16x8*)(lbq + wo1) = sb1;
    __syncthreads();
    if (kt + 1 < NK) {
      const u16* Ak = Ab + (size_t)(kt + 1) * 32;
      const u16* Bk = Bb + (size_t)(kt + 1) * 32;
      na0 = *(const u16x8*)(Ak + (size_t)r0s * K + i0 * 8);
      na1 = *(const u16x8*)(Ak + (size_t)r1s * K + i0 * 8);
      nb0 = *(const u16x8*)(Bk + (size_t)r0s * K + i0 * 8);
      nb1 = *(const u16x8*)(Bk + (size_t)r1s * K + i0 * 8);
    }
    BU af[4], bf_[4];
#pragma unroll
    for (int mi = 0; mi < 4; ++mi) {
      const int row = wm + mi * 16 + lr;
      af[mi].u = *(const u16x8*)(laq + row * 64 + ((lg * 16) ^ SWZ(row)));
      const int rowb = wn + mi * 16 + lr;
      bf_[mi].u = *(const u16x8*)(lbq + rowb * 64 + ((lg * 16) ^ SWZ(rowb)));
    }
#pragma unroll
    for (int mi = 0; mi < 4; ++mi)
#pragma unroll
      for (int ni = 0; ni < 4; ++ni)
        acc[mi][ni] = __builtin_amdgcn_mfma_f32_16x16x32_bf16(af[mi].b, bf_[ni].b,
                                                              acc[mi][ni], 0, 0, 0);
    sa0 = na0; sa1 = na1; sb0 = nb0; sb1 = nb1;
  }

  // C/D layout: col = lane&15, row = (lane>>4)*4 + reg  (m89-verified)
#pragma unroll
  for (int mi = 0; mi < 4; ++mi)
#pragma unroll
    for (int ni = 0; ni < 4; ++ni)
#pragma unroll
      for (int r = 0; r < 4; ++r) {
        const int row = m0 + wm + mi * 16 + lg * 4 + r;
        const int col = n0 + wn + ni * 16 + lr;
        store_c(C, (size_t)row * N + col, acc[mi][ni][r]);
      }
}

// ---------------- RoPE + head layout + V transpose ----------------
// qkv (BS x 3072) bf16 -> Q,K [bh][s][dh] (rope'd), Vt [bh][dh][s]
__global__ __launch_bounds__(256) void k_prep(const u16* __restrict__ qkv,
                                              const float* __restrict__ ct,
                                              const float* __restrict__ st,
                                              u16* __restrict__ Q, u16* __restrict__ K,
                                              u16* __restrict__ Vt) {
  __shared__ u16 vl[64][72];
  const int stile = blockIdx.x, bh = blockIdx.y;
  const int b = bh >> 4, h = bh & 15;
  const int t = threadIdx.x;
  const int row = t >> 2, qr = t & 3;
  const int s = stile * 64 + row;
  const u16* base = qkv + (size_t)(b * S_ + s) * N3_ + h * DH_;
  const int d0 = qr * 8;  // pair-halves d0..d0+7 and +32
  float c[8], sn[8];
#pragma unroll
  for (int j = 0; j < 8; ++j) {
    c[j] = ct[s * 32 + d0 + j];
    sn[j] = st[s * 32 + d0 + j];
  }
#pragma unroll
  for (int part = 0; part < 2; ++part) {
    const u16* src = base + part * D_;
    u16x8 lo = *(const u16x8*)(src + d0);
    u16x8 hi = *(const u16x8*)(src + d0 + 32);
    u16x8 olo, ohi;
#pragma unroll
    for (int j = 0; j < 8; ++j) {
      float x1 = bf2f(lo[j]), x2 = bf2f(hi[j]);
      olo[j] = f2bf(x1 * c[j] - x2 * sn[j]);
      ohi[j] = f2bf(x2 * c[j] + x1 * sn[j]);
    }
    u16* dst = (part ? K : Q) + ((size_t)bh * S_ + s) * DH_;
    *(u16x8*)(dst + d0) = olo;
    *(u16x8*)(dst + d0 + 32) = ohi;
  }
  // V transpose through LDS (64 s-rows x 64 dh -> 64 dh-rows x 64 s)
  u16x8 v0 = *(const u16x8*)(base + 2 * D_ + qr * 16);
  u16x8 v1 = *(const u16x8*)(base + 2 * D_ + qr * 16 + 8);
#pragma unroll
  for (int j = 0; j < 8; ++j) {
    vl[qr * 16 + j][row] = v0[j];
    vl[qr * 16 + 8 + j][row] = v1[j];
  }
  __syncthreads();
  const int dh = row, sc = qr * 16;
  u16x8 o0, o1;
#pragma unroll
  for (int j = 0; j < 8; ++j) { o0[j] = vl[dh][sc + j]; o1[j] = vl[dh][sc + 8 + j]; }
  u16* vdst = Vt + ((size_t)bh * DH_ + dh) * S_ + stile * 64 + sc;
  *(u16x8*)vdst = o0;
  *(u16x8*)(vdst + 8) = o1;
}

// ---------------- causal flash attention, LDS-shared K/V ----------------
// Block = 4 waves, one (bh, 64 q-rows) tile. Per kv-tile of 64: K (8KB) and
// V^T (8KB) staged once into LDS (reg-staged, double-buffered, XOR-swizzled),
// consumed by all 4 waves. Swapped-operand MFMA form as before:
//   S^T = K·Q^T ; O^T = V^T·P^T  (P^T through tiny per-wave LDS buffer).
// XCD-pinned: bid&7 == bh%8 so each XCD's K/V working set (2MB) fits its L2.
__global__ __launch_bounds__(256, 4) void k_attn(const u16* __restrict__ Q,
                                                 const u16* __restrict__ K,
                                                 const u16* __restrict__ Vt,
                                                 u16* __restrict__ Ao) {
  __shared__ char kvb_[2][16384];   // per buf: K tile [64][128B] @0, V^T tile @8192
  __shared__ char plb[4][2048];     // per-wave P: [16 q][128B kv], XOR-swizzled
  const int bid = blockIdx.x;
  const int xcd = bid & 7, inner = bid >> 3;
  const int bh = xcd + 8 * (inner & 3);
  const int qt = 31 - (inner >> 2);          // longest first
  const int t = threadIdx.x;
  const int w = t >> 6, lane = t & 63;
  const int lr = lane & 15, lg = lane >> 4;
  const int q0 = qt * 64 + w * 16;
  const int nt = qt + 1;

  const u16* Kbh = K + (size_t)bh * S_ * DH_;
  const u16* Vbh = Vt + (size_t)bh * DH_ * S_;

  // staging coords: thread t covers rows srow, srow+32 with 16B at byte scol*2
  const int srow = t >> 3;          // 0..31
  const int scol = (t & 7) * 8;     // element offset within 64-wide row

  const u16* Qb = Q + ((size_t)bh * S_ + q0) * DH_;
  BU qf0, qf1;                      // B-operand: Q^T[d=lg*8+j][q=lr]
  qf0.u = *(const u16x8*)(Qb + lr * DH_ + lg * 8);
  qf1.u = *(const u16x8*)(Qb + lr * DH_ + 32 + lg * 8);

  f32x4 o[4] = {};                  // O^T acc: o[d] dh=d*16+lg*4+r, q=lr
  float m = -1e30f, l = 0.f;
  char* plw = plb[w];
  const int psw = (lr & 7) << 4;

  u16x8 kreg[2], vreg[2];
#pragma unroll
  for (int c = 0; c < 2; ++c) {     // prologue: tile 0
    const int row = srow + 32 * c;
    kreg[c] = *(const u16x8*)(Kbh + (size_t)row * DH_ + scol);
    vreg[c] = *(const u16x8*)(Vbh + (size_t)row * S_ + scol);
  }
  {
    char* dst = kvb_[0];
#pragma unroll
    for (int c = 0; c < 2; ++c) {
      const int row = srow + 32 * c;
      const int off = row * 128 + ((scol * 2) ^ ((row & 7) << 4));
      *(u16x8*)(dst + off) = kreg[c];
      *(u16x8*)(dst + 8192 + off) = vreg[c];
    }
  }
  __syncthreads();

  int cur = 0;
  for (int it = 0; it < nt; ++it) {
    const int kv0 = it * 64;
    if (it + 1 < nt) {              // issue next tile's global loads early
      const int kvn = kv0 + 64;
#pragma unroll
      for (int c = 0; c < 2; ++c) {
        const int row = srow + 32 * c;
        kreg[c] = *(const u16x8*)(Kbh + (size_t)(kvn + row) * DH_ + scol);
        vreg[c] = *(const u16x8*)(Vbh + (size_t)row * S_ + kvn + scol);
      }
    }
    const char* base = kvb_[cur];
    f32x4 s[4] = {};
#pragma unroll
    for (int kvbi = 0; kvbi < 4; ++kvbi) {
      const int row = kvbi * 16 + lr;
      const int sw = (lr & 7) << 4;
      BU k0, k1;
      k0.u = *(const u16x8*)(base + row * 128 + ((lg * 16) ^ sw));
      k1.u = *(const u16x8*)(base + row * 128 + ((64 + lg * 16) ^ sw));
      s[kvbi] = __builtin_amdgcn_mfma_f32_16x16x32_bf16(k0.b, qf0.b, s[kvbi], 0, 0, 0);
      s[kvbi] = __builtin_amdgcn_mfma_f32_16x16x32_bf16(k1.b, qf1.b, s[kvbi], 0, 0, 0);
    }
    float p[16];
#pragma unroll
    for (int kvbi = 0; kvbi < 4; ++kvbi)
#pragma unroll
      for (int r = 0; r < 4; ++r) p[kvbi * 4 + r] = s[kvbi][r] * 0.125f;
    if (it == nt - 1) {             // only diagonal-crossing tile masks
#pragma unroll
      for (int kvbi = 0; kvbi < 4; ++kvbi)
#pragma unroll
        for (int r = 0; r < 4; ++r)
          if (kv0 + kvbi * 16 + lg * 4 + r > q0 + lr) p[kvbi * 4 + r] = -1e30f;
    }
    float mx = p[0];
#pragma unroll
    for (int i = 1; i < 16; ++i) mx = fmaxf(mx, p[i]);
    mx = fmaxf(mx, __shfl_xor(mx, 16, 64));
    mx = fmaxf(mx, __shfl_xor(mx, 32, 64));
    const float mn = fmaxf(m, mx);
    const float al = __expf(m - mn);
    m = mn;
    float sm = 0.f;
#pragma unroll
    for (int i = 0; i < 16; ++i) { p[i] = __expf(p[i] - mn); sm += p[i]; }
    sm += __shfl_xor(sm, 16, 64);
    sm += __shfl_xor(sm, 32, 64);
    l = l * al + sm;
#pragma unroll
    for (int d = 0; d < 4; ++d)
#pragma unroll
      for (int r = 0; r < 4; ++r) o[d][r] *= al;
    // P[q=lr][kv] -> per-wave LDS (swizzled), read back as B-fragments
#pragma unroll
    for (int kvbi = 0; kvbi < 4; ++kvbi) {
      u16x4 w4;
#pragma unroll
      for (int r = 0; r < 4; ++r) w4[r] = f2bf(p[kvbi * 4 + r]);
      *(u16x4*)(plw + lr * 128 + ((kvbi * 32 + lg * 8) ^ psw)) = w4;
    }
    BU pf0, pf1;
    pf0.u = *(const u16x8*)(plw + lr * 128 + ((lg * 16) ^ psw));
    pf1.u = *(const u16x8*)(plw + lr * 128 + ((64 + lg * 16) ^ psw));
#pragma unroll
    for (int d = 0; d < 4; ++d) {
      const int row = d * 16 + lr;
      const int sw = (lr & 7) << 4;
      BU v0, v1;
      v0.u = *(const u16x8*)(base + 8192 + row * 128 + ((lg * 16) ^ sw));
      v1.u = *(const u16x8*)(base + 8192 + row * 128 + ((64 + lg * 16) ^ sw));
      o[d] = __builtin_amdgcn_mfma_f32_16x16x32_bf16(v0.b, pf0.b, o[d], 0, 0, 0);
      o[d] = __builtin_amdgcn_mfma_f32_16x16x32_bf16(v1.b, pf1.b, o[d], 0, 0, 0);
    }
    if (it + 1 < nt) {              // write next tile, one barrier per iter
      char* dst = kvb_[cur ^ 1];
#pragma unroll
      for (int c = 0; c < 2; ++c) {
        const int row = srow + 32 * c;
        const int off = row * 128 + ((scol * 2) ^ ((row & 7) << 4));
        *(u16x8*)(dst + off) = kreg[c];
        *(u16x8*)(dst + 8192 + off) = vreg[c];
      }
      __syncthreads();
    }
    cur ^= 1;
  }

  const float inv = 1.0f / l;
  const int b = bh >> 4, h = bh & 15;
  const size_t rowo = ((size_t)b * S_ + q0 + lr) * D_ + h * DH_;
#pragma unroll
  for (int d = 0; d < 4; ++d) {
    u16x4 w4;
#pragma unroll
    for (int r = 0; r < 4; ++r) w4[r] = f2bf(o[d][r] * inv);
    *(u16x4*)(Ao + rowo + d * 16 + lg * 4) = w4;
  }
}

// ---------------- launch ----------------
extern "C" void kernel_launch(void* const* d_in, const int* in_sizes, int n_in,
                              void* d_out, int out_size, void* d_ws, size_t ws_size,
                              hipStream_t stream) {
  const float* x = (const float*)d_in[0];
  const float* wqkv = (const float*)d_in[1];
  const float* wproj = (const float*)d_in[2];
  float* out = (float*)d_out;
  char* ws = (char*)d_ws;

  // workspace layout (~76 MB total)
  u16* xb      = (u16*)(ws + 0);          //  8 MB  x bf16 (4096x1024)
  u16* wqkvT   = (u16*)(ws + 8388608);    //  6 MB  w_qkv^T bf16 (3072x1024)
  u16* wprojT  = (u16*)(ws + 14680064);   //  2 MB  w_proj^T bf16 (1024x1024)
  u16* qkvb    = (u16*)(ws + 16777216);   // 24 MB  qkv bf16 (4096x3072)
  u16* Qb      = (u16*)(ws + 41943040);   //  8 MB  [bh][s][dh]
  u16* Kb      = (u16*)(ws + 50331648);   //  8 MB  [bh][s][dh]
  u16* Vtb     = (u16*)(ws + 58720256);   //  8 MB  [bh][dh][s]
  u16* aob     = (u16*)(ws + 67108864);   //  8 MB  attn out (4096x1024)
  float* ct    = (float*)(ws + 75497472); // 256 KB cos table (S x 32)
  float* stab  = (float*)(ws + 75759616); // 256 KB sin table

  k_cvt<<<4096, 256, 0, stream>>>(x, xb, BS_ * D_ / 4);
  k_cvt_T<<<dim3(96, 32), 256, 0, stream>>>(wqkv, wqkvT, D_, N3_);
  k_cvt_T<<<dim3(32, 32), 256, 0, stream>>>(wproj, wprojT, D_, D_);
  k_tab<<<256, 256, 0, stream>>>(ct, stab);

  k_gemm<u16><<<dim3(24, 32), 256, 0, stream>>>(xb, wqkvT, qkvb, BS_, N3_, D_);
  k_prep<<<dim3(32, 32), 256, 0, stream>>>(qkvb, ct, stab, Qb, Kb, Vtb);
  k_attn<<<1024, 256, 0, stream>>>(Qb, Kb, Vtb, aob);
  k_gemm<float><<<dim3(8, 32), 256, 0, stream>>>(aob, wprojT, out, BS_, D_, D_);
}